// Round 4
// baseline (220.348 us; speedup 1.0000x reference)
//
#include <hip/hip_runtime.h>

#define BROWS 8192
#define TLEN  1024
#define GRID_A 512              // 4 waves/block -> 2048 waves, 4 rows each
#define GRID_B 1024             // 8 rows per block, uniform row per iteration
#define ITER_B (BROWS / GRID_B) // 8

// d_ws layout:
//   [0..8)    double sum_acc
//   [8..16)   double cnt_acc
//   [16..20)  int    arrive
//   [64..)    int    fz[BROWS]

// ---------------- Kernel A: persistent fz + count --------------------------
__global__ __launch_bounds__(256) void fz_kernel(
    const int* __restrict__ seq,
    int*       __restrict__ fz_out,
    double*    __restrict__ cnt_acc)
{
    const int wave = threadIdx.x >> 6;
    const int lane = threadIdx.x & 63;
    const int wid  = blockIdx.x * 4 + wave;      // 0..2047

    double c = 0.0;
    #pragma unroll
    for (int it = 0; it < 4; ++it) {
        const int row = wid + it * 2048;
        const int4* s4 = (const int4*)(seq + (size_t)row * TLEN);
        int4 s[4];
        #pragma unroll
        for (int k = 0; k < 4; ++k)
            s[k] = s4[k * 64 + lane];

        // First zero among this lane's 16 tokens; descending overwrite ->
        // smallest index wins. TLEN = "none".
        int fz = TLEN;
        #pragma unroll
        for (int k = 3; k >= 0; --k) {
            const int base = k * 256 + lane * 4;
            if (s[k].w == 0) fz = base + 3;
            if (s[k].z == 0) fz = base + 2;
            if (s[k].y == 0) fz = base + 1;
            if (s[k].x == 0) fz = base + 0;
        }
        #pragma unroll
        for (int off = 32; off > 0; off >>= 1)
            fz = min(fz, __shfl_xor(fz, off, 64));

        if (lane == 0) {
            fz_out[row] = fz;
            c += (double)min(fz + 1, TLEN);      // valid-token count of row
        }
    }
    if (lane == 0)
        atomicAdd(cnt_acc, c);                   // device-scope f64 atomic
}

// ---------------- Kernel B: persistent masked sum + finalize ---------------
__global__ __launch_bounds__(256) void sum_kernel(
    const float* __restrict__ logp,
    const float* __restrict__ value,
    const float* __restrict__ reward,
    const int*   __restrict__ fz_in,
    double*      __restrict__ sum_acc,
    double*      __restrict__ cnt_acc,
    int*         __restrict__ arrive,
    float*       __restrict__ out)
{
    const int tid = threadIdx.x;
    const int t0  = tid * 4;

    double acc = 0.0;
    #pragma unroll 2
    for (int it = 0; it < ITER_B; ++it) {
        const int row = blockIdx.x + it * GRID_B;   // block-uniform
        const int fz  = fz_in[row];                 // uniform -> L1 broadcast
        const size_t off = (size_t)row * TLEN;
        const float4 l = ((const float4*)(logp   + off))[tid];
        const float4 v = ((const float4*)(value  + off))[tid];
        const float4 r = ((const float4*)(reward + off))[tid];
        // mask[t] = 1 iff t <= fz (verified absmax 0.0 in prior rounds)
        if (t0 + 0 <= fz) acc += (double)(-l.x * (r.x - v.x));
        if (t0 + 1 <= fz) acc += (double)(-l.y * (r.y - v.y));
        if (t0 + 2 <= fz) acc += (double)(-l.z * (r.z - v.z));
        if (t0 + 3 <= fz) acc += (double)(-l.w * (r.w - v.w));
    }

    // Block reduce: wave butterfly + LDS.
    #pragma unroll
    for (int off = 32; off > 0; off >>= 1)
        acc += __shfl_xor(acc, off, 64);
    __shared__ double ls[4];
    if ((tid & 63) == 0) ls[tid >> 6] = acc;
    __syncthreads();

    if (tid == 0) {
        atomicAdd(sum_acc, ls[0] + ls[1] + ls[2] + ls[3]);
        __threadfence();
        const int old = atomicAdd(arrive, 1);
        if (old == GRID_B - 1) {
            // Last block: all sum-adds happened-before their arrive-adds.
            const double s = atomicAdd(sum_acc, 0.0);   // coherent read
            const double c = atomicAdd(cnt_acc, 0.0);
            out[0] = (float)(s / c);
        }
    }
}

extern "C" void kernel_launch(void* const* d_in, const int* in_sizes, int n_in,
                              void* d_out, int out_size, void* d_ws, size_t ws_size,
                              hipStream_t stream) {
    const int*   seq    = (const int*)  d_in[0];
    const float* logp   = (const float*)d_in[1];
    const float* value  = (const float*)d_in[2];
    const float* reward = (const float*)d_in[3];
    float* out = (float*)d_out;

    double* sum_acc = (double*)d_ws;
    double* cnt_acc = sum_acc + 1;
    int*    arrive  = (int*)((char*)d_ws + 16);
    int*    fz      = (int*)((char*)d_ws + 64);

    hipMemsetAsync(d_ws, 0, 24, stream);   // zero sum/cnt/arrive (graph-legal)

    fz_kernel <<<GRID_A, 256, 0, stream>>>(seq, fz, cnt_acc);
    sum_kernel<<<GRID_B, 256, 0, stream>>>(logp, value, reward, fz,
                                           sum_acc, cnt_acc, arrive, out);
}

// Round 5
// 155.851 us; speedup vs baseline: 1.4138x; 1.4138x over previous
//
#include <hip/hip_runtime.h>

#define BROWS 8192
#define TLEN  1024

// One block per row (8192 one-shot blocks — the best-measured configuration).
// All 16 loads per thread issued before any dependent compute; f32 math only;
// branchless predication; ballot-based first-zero (1 ballot + 1 shuffle
// instead of a 6-deep shuffle-min chain).
__global__ __launch_bounds__(256) void row_reduce_kernel(
    const int*   __restrict__ seq,
    const float* __restrict__ logp,
    const float* __restrict__ value,
    const float* __restrict__ reward,
    float*       __restrict__ row_sum,
    float*       __restrict__ row_cnt)
{
    const int b    = blockIdx.x;
    const int tid  = threadIdx.x;
    const int lane = tid & 63;
    const int wave = tid >> 6;

    const size_t rowoff = (size_t)b * TLEN;

    // Issue ALL loads up-front (64 data VGPRs) to maximize in-flight vmem.
    const int4   s = ((const int4*)  (seq    + rowoff))[tid];
    const float4 l = ((const float4*)(logp   + rowoff))[tid];
    const float4 v = ((const float4*)(value  + rowoff))[tid];
    const float4 r = ((const float4*)(reward + rowoff))[tid];

    // Local first-zero among this thread's 4 tokens: 0..3, or 4 if none.
    int lfz = 4;
    if (s.w == 0) lfz = 3;
    if (s.z == 0) lfz = 2;
    if (s.y == 0) lfz = 1;
    if (s.x == 0) lfz = 0;

    // Wave-level first zero via ballot (uniform across the wave).
    const unsigned long long has = __ballot(lfz < 4);
    int wfz = TLEN;
    if (has) {
        const int fl  = __ffsll((long long)has) - 1;   // first lane with a zero
        const int flz = __shfl(lfz, fl, 64);           // its local index
        wfz = (wave * 64 + fl) * 4 + flz;
    }

    // Cross-wave min (4 waves) through LDS.
    __shared__ int   lds_fz[4];
    __shared__ float lds_sum[4];
    if (lane == 0) lds_fz[wave] = wfz;
    __syncthreads();
    const int fz = min(min(lds_fz[0], lds_fz[1]), min(lds_fz[2], lds_fz[3]));

    // Branchless masked products, 4 independent f32 accumulator chains.
    // mask[t] = 1 iff t <= fz  (verified absmax 0.0 in earlier rounds).
    const int t0 = tid * 4;
    const float p0 = (t0 + 0 <= fz) ? (-l.x * (r.x - v.x)) : 0.0f;
    const float p1 = (t0 + 1 <= fz) ? (-l.y * (r.y - v.y)) : 0.0f;
    const float p2 = (t0 + 2 <= fz) ? (-l.z * (r.z - v.z)) : 0.0f;
    const float p3 = (t0 + 3 <= fz) ? (-l.w * (r.w - v.w)) : 0.0f;
    float acc = (p0 + p1) + (p2 + p3);

    // Wave f32 butterfly sum, then cross-wave via LDS.
    #pragma unroll
    for (int off = 32; off > 0; off >>= 1)
        acc += __shfl_xor(acc, off, 64);

    if (lane == 0) lds_sum[wave] = acc;
    __syncthreads();
    if (tid == 0) {
        row_sum[b] = (lds_sum[0] + lds_sum[1]) + (lds_sum[2] + lds_sum[3]);
        row_cnt[b] = (float)min(fz + 1, TLEN);
    }
}

// Single block: deterministic f64 reduce of 8192 row partials -> scalar.
__global__ __launch_bounds__(256) void final_reduce_kernel(
    const float* __restrict__ row_sum,
    const float* __restrict__ row_cnt,
    float*       __restrict__ out)
{
    const int tid  = threadIdx.x;
    const int lane = tid & 63;
    const int wave = tid >> 6;

    double s = 0.0, c = 0.0;
    for (int i = tid; i < BROWS; i += 256) {
        s += (double)row_sum[i];
        c += (double)row_cnt[i];
    }
    #pragma unroll
    for (int off = 32; off > 0; off >>= 1) {
        s += __shfl_xor(s, off, 64);
        c += __shfl_xor(c, off, 64);
    }
    __shared__ double ls[4], lc[4];
    if (lane == 0) { ls[wave] = s; lc[wave] = c; }
    __syncthreads();
    if (tid == 0) {
        double ts = (ls[0] + ls[1]) + (ls[2] + ls[3]);
        double tc = (lc[0] + lc[1]) + (lc[2] + lc[3]);
        out[0] = (float)(ts / tc);
    }
}

extern "C" void kernel_launch(void* const* d_in, const int* in_sizes, int n_in,
                              void* d_out, int out_size, void* d_ws, size_t ws_size,
                              hipStream_t stream) {
    const int*   seq    = (const int*)  d_in[0];
    const float* logp   = (const float*)d_in[1];
    const float* value  = (const float*)d_in[2];
    const float* reward = (const float*)d_in[3];
    float* out = (float*)d_out;

    float* row_sum = (float*)d_ws;            // 8192 * 4 B
    float* row_cnt = row_sum + BROWS;         // 8192 * 4 B

    row_reduce_kernel<<<BROWS, 256, 0, stream>>>(seq, logp, value, reward,
                                                 row_sum, row_cnt);
    final_reduce_kernel<<<1, 256, 0, stream>>>(row_sum, row_cnt, out);
}

// Round 6
// 149.314 us; speedup vs baseline: 1.4757x; 1.0438x over previous
//
#include <hip/hip_runtime.h>

#define BROWS 8192
#define TLEN  1024

typedef float f32x4 __attribute__((ext_vector_type(4)));
typedef int   i32x4 __attribute__((ext_vector_type(4)));

// One block per row, 8192 one-shot blocks — best-measured configuration.
// Identical to round 5 except: all global reads are NONTEMPORAL (nt bit on
// global_load_dwordx4) — streaming data is read exactly once, so skip cache
// allocation. This is the only changed variable vs round 5's 44.2 us.
__global__ __launch_bounds__(256) void row_reduce_kernel(
    const int*   __restrict__ seq,
    const float* __restrict__ logp,
    const float* __restrict__ value,
    const float* __restrict__ reward,
    float*       __restrict__ row_sum,
    float*       __restrict__ row_cnt)
{
    const int b    = blockIdx.x;
    const int tid  = threadIdx.x;
    const int lane = tid & 63;
    const int wave = tid >> 6;

    const size_t rowoff = (size_t)b * TLEN;

    // Issue ALL loads up-front, nontemporal (no L1/L2 allocate, still probes).
    const i32x4 s = __builtin_nontemporal_load((const i32x4*)(seq    + rowoff) + tid);
    const f32x4 l = __builtin_nontemporal_load((const f32x4*)(logp   + rowoff) + tid);
    const f32x4 v = __builtin_nontemporal_load((const f32x4*)(value  + rowoff) + tid);
    const f32x4 r = __builtin_nontemporal_load((const f32x4*)(reward + rowoff) + tid);

    // Local first-zero among this thread's 4 tokens: 0..3, or 4 if none.
    int lfz = 4;
    if (s[3] == 0) lfz = 3;
    if (s[2] == 0) lfz = 2;
    if (s[1] == 0) lfz = 1;
    if (s[0] == 0) lfz = 0;

    // Wave-level first zero via ballot (uniform across the wave).
    const unsigned long long has = __ballot(lfz < 4);
    int wfz = TLEN;
    if (has) {
        const int fl  = __ffsll((long long)has) - 1;   // first lane with a zero
        const int flz = __shfl(lfz, fl, 64);           // its local index
        wfz = (wave * 64 + fl) * 4 + flz;
    }

    // Cross-wave min (4 waves) through LDS.
    __shared__ int   lds_fz[4];
    __shared__ float lds_sum[4];
    if (lane == 0) lds_fz[wave] = wfz;
    __syncthreads();
    const int fz = min(min(lds_fz[0], lds_fz[1]), min(lds_fz[2], lds_fz[3]));

    // Branchless masked products. mask[t] = 1 iff t <= fz (absmax 0.0 prior).
    const int t0 = tid * 4;
    const float p0 = (t0 + 0 <= fz) ? (-l[0] * (r[0] - v[0])) : 0.0f;
    const float p1 = (t0 + 1 <= fz) ? (-l[1] * (r[1] - v[1])) : 0.0f;
    const float p2 = (t0 + 2 <= fz) ? (-l[2] * (r[2] - v[2])) : 0.0f;
    const float p3 = (t0 + 3 <= fz) ? (-l[3] * (r[3] - v[3])) : 0.0f;
    float acc = (p0 + p1) + (p2 + p3);

    // Wave f32 butterfly sum, then cross-wave via LDS.
    #pragma unroll
    for (int off = 32; off > 0; off >>= 1)
        acc += __shfl_xor(acc, off, 64);

    if (lane == 0) lds_sum[wave] = acc;
    __syncthreads();
    if (tid == 0) {
        row_sum[b] = (lds_sum[0] + lds_sum[1]) + (lds_sum[2] + lds_sum[3]);
        row_cnt[b] = (float)min(fz + 1, TLEN);
    }
}

// Single block: deterministic f64 reduce of 8192 row partials -> scalar.
__global__ __launch_bounds__(256) void final_reduce_kernel(
    const float* __restrict__ row_sum,
    const float* __restrict__ row_cnt,
    float*       __restrict__ out)
{
    const int tid  = threadIdx.x;
    const int lane = tid & 63;
    const int wave = tid >> 6;

    double s = 0.0, c = 0.0;
    for (int i = tid; i < BROWS; i += 256) {
        s += (double)row_sum[i];
        c += (double)row_cnt[i];
    }
    #pragma unroll
    for (int off = 32; off > 0; off >>= 1) {
        s += __shfl_xor(s, off, 64);
        c += __shfl_xor(c, off, 64);
    }
    __shared__ double ls[4], lc[4];
    if (lane == 0) { ls[wave] = s; lc[wave] = c; }
    __syncthreads();
    if (tid == 0) {
        double ts = (ls[0] + ls[1]) + (ls[2] + ls[3]);
        double tc = (lc[0] + lc[1]) + (lc[2] + lc[3]);
        out[0] = (float)(ts / tc);
    }
}

extern "C" void kernel_launch(void* const* d_in, const int* in_sizes, int n_in,
                              void* d_out, int out_size, void* d_ws, size_t ws_size,
                              hipStream_t stream) {
    const int*   seq    = (const int*)  d_in[0];
    const float* logp   = (const float*)d_in[1];
    const float* value  = (const float*)d_in[2];
    const float* reward = (const float*)d_in[3];
    float* out = (float*)d_out;

    float* row_sum = (float*)d_ws;            // 8192 * 4 B
    float* row_cnt = row_sum + BROWS;         // 8192 * 4 B

    row_reduce_kernel<<<BROWS, 256, 0, stream>>>(seq, logp, value, reward,
                                                 row_sum, row_cnt);
    final_reduce_kernel<<<1, 256, 0, stream>>>(row_sum, row_cnt, out);
}

// Round 7
// 147.563 us; speedup vs baseline: 1.4932x; 1.0119x over previous
//
#include <hip/hip_runtime.h>

#define BROWS 8192
#define TLEN  1024

typedef float f32x4 __attribute__((ext_vector_type(4)));
typedef int   i32x4 __attribute__((ext_vector_type(4)));

// One wave per row; 4 rows per 256-thread block; grid = 2048. Each lane owns
// 16 tokens (4 x int4/float4 per array), ALL 16 nontemporal loads issued
// up-front. Zero LDS, zero barriers — the entire row reduction is wave-local
// (1 ballot + 1 shuffle for first-zero, 6-shuffle f32 butterfly for the sum).
__global__ __launch_bounds__(256) void row_reduce_kernel(
    const int*   __restrict__ seq,
    const float* __restrict__ logp,
    const float* __restrict__ value,
    const float* __restrict__ reward,
    float*       __restrict__ row_sum,
    float*       __restrict__ row_cnt)
{
    const int row  = blockIdx.x * 4 + (threadIdx.x >> 6);
    const int lane = threadIdx.x & 63;

    const size_t rowoff = (size_t)row * TLEN;
    const i32x4* s4 = (const i32x4*)(seq    + rowoff);
    const f32x4* l4 = (const f32x4*)(logp   + rowoff);
    const f32x4* v4 = (const f32x4*)(value  + rowoff);
    const f32x4* r4 = (const f32x4*)(reward + rowoff);

    i32x4 s[4];
    f32x4 l[4], v[4], r[4];
    #pragma unroll
    for (int k = 0; k < 4; ++k) {
        const int idx = k * 64 + lane;          // coalesced 1KB/wave per load
        s[k] = __builtin_nontemporal_load(s4 + idx);
        l[k] = __builtin_nontemporal_load(l4 + idx);
        v[k] = __builtin_nontemporal_load(v4 + idx);
        r[k] = __builtin_nontemporal_load(r4 + idx);
    }

    // Per-lane first-zero among its 16 tokens (absolute index; TLEN = none).
    // Descending overwrite -> smallest index wins.
    int lfz = TLEN;
    #pragma unroll
    for (int k = 3; k >= 0; --k) {
        const int base = k * 256 + lane * 4;
        if (s[k][3] == 0) lfz = base + 3;
        if (s[k][2] == 0) lfz = base + 2;
        if (s[k][1] == 0) lfz = base + 1;
        if (s[k][0] == 0) lfz = base + 0;
    }

    // Wave first-zero: ballot + shuffle from the first lane that has one.
    // (Lane order != token order across k-iterations, but every lane's lfz is
    // its own MINIMUM zero index; the row minimum is min over lanes with a
    // zero. Lane fl = first set bit has the smallest lane index, NOT
    // necessarily the smallest token index — so take min over candidates
    // via a short butterfly on lfz instead; still branch-free and correct.)
    int fz = lfz;
    #pragma unroll
    for (int off = 32; off > 0; off >>= 1)
        fz = min(fz, __shfl_xor(fz, off, 64));

    // Branchless masked products, 4 independent f32 chains per lane.
    // mask[t] = 1 iff t <= fz (verified absmax 0.0 across rounds 1-6).
    float a0 = 0.0f, a1 = 0.0f, a2 = 0.0f, a3 = 0.0f;
    #pragma unroll
    for (int k = 0; k < 4; ++k) {
        const int base = k * 256 + lane * 4;
        a0 += (base + 0 <= fz) ? (-l[k][0] * (r[k][0] - v[k][0])) : 0.0f;
        a1 += (base + 1 <= fz) ? (-l[k][1] * (r[k][1] - v[k][1])) : 0.0f;
        a2 += (base + 2 <= fz) ? (-l[k][2] * (r[k][2] - v[k][2])) : 0.0f;
        a3 += (base + 3 <= fz) ? (-l[k][3] * (r[k][3] - v[k][3])) : 0.0f;
    }
    float acc = (a0 + a1) + (a2 + a3);

    // Wave f32 butterfly sum.
    #pragma unroll
    for (int off = 32; off > 0; off >>= 1)
        acc += __shfl_xor(acc, off, 64);

    if (lane == 0) {
        row_sum[row] = acc;
        row_cnt[row] = (float)min(fz + 1, TLEN);
    }
}

// Single block: deterministic f64 reduce of 8192 row partials -> scalar.
__global__ __launch_bounds__(256) void final_reduce_kernel(
    const float* __restrict__ row_sum,
    const float* __restrict__ row_cnt,
    float*       __restrict__ out)
{
    const int tid  = threadIdx.x;
    const int lane = tid & 63;
    const int wave = tid >> 6;

    double s = 0.0, c = 0.0;
    for (int i = tid; i < BROWS; i += 256) {
        s += (double)row_sum[i];
        c += (double)row_cnt[i];
    }
    #pragma unroll
    for (int off = 32; off > 0; off >>= 1) {
        s += __shfl_xor(s, off, 64);
        c += __shfl_xor(c, off, 64);
    }
    __shared__ double ls[4], lc[4];
    if (lane == 0) { ls[wave] = s; lc[wave] = c; }
    __syncthreads();
    if (tid == 0) {
        double ts = (ls[0] + ls[1]) + (ls[2] + ls[3]);
        double tc = (lc[0] + lc[1]) + (lc[2] + lc[3]);
        out[0] = (float)(ts / tc);
    }
}

extern "C" void kernel_launch(void* const* d_in, const int* in_sizes, int n_in,
                              void* d_out, int out_size, void* d_ws, size_t ws_size,
                              hipStream_t stream) {
    const int*   seq    = (const int*)  d_in[0];
    const float* logp   = (const float*)d_in[1];
    const float* value  = (const float*)d_in[2];
    const float* reward = (const float*)d_in[3];
    float* out = (float*)d_out;

    float* row_sum = (float*)d_ws;            // 8192 * 4 B
    float* row_cnt = row_sum + BROWS;         // 8192 * 4 B

    row_reduce_kernel<<<BROWS / 4, 256, 0, stream>>>(seq, logp, value, reward,
                                                     row_sum, row_cnt);
    final_reduce_kernel<<<1, 256, 0, stream>>>(row_sum, row_cnt, out);
}